// Round 13
// baseline (206.145 us; speedup 1.0000x reference)
//
#include <hip/hip_runtime.h>
#include <math.h>

// Problem constants (T5 encoder self-attention)
#define H_    16
#define S_    2048
#define DH_   64
#define DM_   1024
#define NTOK_ 4096          // B*S
#define NBIAS_ 4095         // 2*S-1 distinct relative positions

typedef __attribute__((ext_vector_type(8))) short short8;  // 8 bf16 (4 VGPRs)
typedef __attribute__((ext_vector_type(4))) float f32x4;   // MFMA C/D frag

#define MFMA16(a, b, c) __builtin_amdgcn_mfma_f32_16x16x32_bf16((a), (b), (c), 0, 0, 0)

#if __has_builtin(__builtin_amdgcn_exp2f)
#define EXP2(x) __builtin_amdgcn_exp2f(x)
#else
#define EXP2(x) exp2f(x)
#endif

__device__ __forceinline__ ushort f2bf(float f) {
  union { float f; unsigned u; } x; x.f = f;
  unsigned r = (x.u + 0x7FFFu + ((x.u >> 16) & 1u)) >> 16;  // RNE
  return (ushort)r;
}
__device__ __forceinline__ ushort f2bf_fast(float f) {       // round-half-up (2 VALU)
  union { float f; unsigned u; } x; x.f = f;
  return (ushort)((x.u + 0x8000u) >> 16);
}

// global (16B per lane) -> LDS, async. LDS dest = wave-uniform base + lane*16.
__device__ __forceinline__ void ldg16_lds(const ushort* g, ushort* l) {
  __builtin_amdgcn_global_load_lds(
      (const __attribute__((address_space(1))) unsigned int*)g,
      (__attribute__((address_space(3))) unsigned int*)l, 16, 0, 0);
}

// ---------------- prep: fp32 -> bf16 cast (8192 one-shot blocks, R9/R12-exact code)
// + bias table in one extra block. R11 bundled this fusion WITH a grid-stride cast
// rewrite and regressed; this isolates the fusion (cast dispatch shape unchanged).
#define CAST_BLKS 8192     // (NTOK_*DM_ + 4*DM_*DM_) / (4*256)
__global__ void prep_k(const float* __restrict__ hs,
                       const float* __restrict__ wq, const float* __restrict__ wk,
                       const float* __restrict__ wv, const float* __restrict__ wo,
                       ushort* __restrict__ out, float* __restrict__ biasTab,
                       const float* __restrict__ rel_emb) {
  if (blockIdx.x == CAST_BLKS) {
    // ---- bias table: biasTab[h][delta+2047] = rel_emb[bucket(delta)][h] * log2(e) ----
    for (int d = threadIdx.x; d < NBIAS_; d += 256) {
      int rp = d - (S_ - 1);
      int ret = (rp > 0) ? 16 : 0;
      int arp = rp < 0 ? -rp : rp;
      int bucket;
      if (arp < 8) {
        bucket = ret + arp;
      } else {
        float t = logf((float)arp * 0.125f);
        t = t / 2.772588722239781f;
        t = t * 8.0f;
        int large = 8 + (int)t;
        if (large > 15) large = 15;
        bucket = ret + large;
      }
      for (int h = 0; h < H_; ++h)
        biasTab[h * NBIAS_ + d] = rel_emb[bucket * H_ + h] * 1.4426950408889634f;
    }
    return;
  }
  int i = (blockIdx.x * blockDim.x + threadIdx.x) * 4;
  const float* src;
  int off;
  if (i < NTOK_ * DM_) {
    src = hs; off = i;
  } else {
    int j = i - NTOK_ * DM_;
    int w = j >> 20;                           // DM_*DM_ = 2^20
    off = j & ((DM_ * DM_) - 1);
    src = (w == 0) ? wq : (w == 1) ? wk : (w == 2) ? wv : wo;
  }
  const float4 v = *(const float4*)(src + off);
  ushort4 o;
  o.x = f2bf(v.x); o.y = f2bf(v.y); o.z = f2bf(v.z); o.w = f2bf(v.w);
  *(ushort4*)(out + i) = o;
}

// ---------------- QKV projection, z-FUSED (R12-exact, validated): one X stage, 3 W panels ----------------
// Per k-step per wave: 24 MFMA : 10 ds_read : 5 stage chunks. Tile 128(M) x 64(N) x 3 outputs;
// grid (16,32) = 512 = 2/CU; LDS 20KB. Q pre-scaled 0.125*log2e.
__global__ __launch_bounds__(256) void gemm_qkv_k(
    const ushort* __restrict__ X,
    const ushort* __restrict__ Wq, const ushort* __restrict__ Wk, const ushort* __restrict__ Wv,
    ushort* __restrict__ Q, ushort* __restrict__ K, ushort* __restrict__ Vt)
{
  __shared__ __align__(16) ushort As[128 * 32];      // 8 KB
  __shared__ __align__(16) ushort Bs[3][64 * 32];    // 12 KB (one 64-row panel per weight)

  const int tid = threadIdx.x;
  const int wave = tid >> 6, lane = tid & 63;
  const int l15 = lane & 15, l4 = lane >> 4;
  const int wm = wave >> 1, wn = wave & 1;
  const int m0 = blockIdx.y * 128;
  const int n0 = blockIdx.x * 64;
  const int srow = lane >> 2, scol = (lane & 3) * 8;

  f32x4 acc[3][4][2];
#pragma unroll
  for (int p = 0; p < 3; ++p)
#pragma unroll
    for (int mi = 0; mi < 4; ++mi)
#pragma unroll
      for (int ni = 0; ni < 2; ++ni) acc[p][mi][ni] = (f32x4){0.f, 0.f, 0.f, 0.f};

  for (int k0 = 0; k0 < DM_; k0 += 32) {
    __syncthreads();   // previous iter's LDS readers done
#pragma unroll
    for (int i = 0; i < 5; ++i) {
      int c = wave * 5 + i;                 // 0..19: 8 A-chunks then 3x4 B-chunks
      if (c < 8) {
        ldg16_lds(X + (size_t)(m0 + c * 16 + srow) * DM_ + k0 + scol, &As[c * 512]);
      } else {
        int j = c - 8;                      // 0..11
        int p = j >> 2, q = j & 3;          // panel, chunk
        const ushort* Wp = (p == 0) ? Wq : (p == 1) ? Wk : Wv;
        ldg16_lds(Wp + (size_t)(n0 + q * 16 + srow) * DM_ + k0 + scol, &Bs[p][q * 512]);
      }
    }
    __syncthreads();   // drains vmcnt (global_load_lds complete)
    short8 af[4], bf[3][2];
#pragma unroll
    for (int mi = 0; mi < 4; ++mi)
      af[mi] = *(const short8*)&As[(wm * 64 + mi * 16 + l15) * 32 + l4 * 8];
#pragma unroll
    for (int p = 0; p < 3; ++p)
#pragma unroll
      for (int ni = 0; ni < 2; ++ni)
        bf[p][ni] = *(const short8*)&Bs[p][(wn * 32 + ni * 16 + l15) * 32 + l4 * 8];
#pragma unroll
    for (int p = 0; p < 3; ++p)
#pragma unroll
      for (int mi = 0; mi < 4; ++mi)
#pragma unroll
        for (int ni = 0; ni < 2; ++ni)
          acc[p][mi][ni] = MFMA16(af[mi], bf[p][ni], acc[p][mi][ni]);
  }

#pragma unroll
  for (int p = 0; p < 3; ++p) {
    const float scl = (p == 0) ? 0.1803368801111137f : 1.0f;  // 0.125 * log2(e) for Q
#pragma unroll
    for (int mi = 0; mi < 4; ++mi)
#pragma unroll
      for (int ni = 0; ni < 2; ++ni)
#pragma unroll
        for (int r = 0; r < 4; ++r) {
          int m = m0 + wm * 64 + mi * 16 + l4 * 4 + r;
          int n = n0 + wn * 32 + ni * 16 + l15;
          int b = m >> 11, s = m & (S_ - 1);
          int h = n >> 6, d = n & 63;
          ushort bv = f2bf(acc[p][mi][ni][r] * scl);
          if (p == 0)      Q [((size_t)(b * H_ + h) * S_ + s) * DH_ + d] = bv;
          else if (p == 1) K [((size_t)(b * H_ + h) * S_ + s) * DH_ + d] = bv;
          else             Vt[((size_t)(b * H_ + h) * DH_ + d) * S_ + s] = bv;
        }
  }
}

// ---------------- Output projection: out = Ctx @ Wo^T (fp32 out, R5/R9/R12-exact) ----------------
__global__ __launch_bounds__(256) void gemm_out_k(
    const ushort* __restrict__ A, const ushort* __restrict__ W, float* __restrict__ out)
{
  __shared__ __align__(16) ushort As[128 * 32];
  __shared__ __align__(16) ushort Bs[128 * 32];
  const int tid = threadIdx.x;
  const int wave = tid >> 6, lane = tid & 63;
  const int l15 = lane & 15, l4 = lane >> 4;
  const int wm = wave >> 1, wn = wave & 1;
  const int m0 = blockIdx.y * 128;
  const int n0 = blockIdx.x * 128;
  const int srow = lane >> 2, scol = (lane & 3) * 8;

  f32x4 acc[4][4];
#pragma unroll
  for (int mi = 0; mi < 4; ++mi)
#pragma unroll
    for (int ni = 0; ni < 4; ++ni) acc[mi][ni] = (f32x4){0.f, 0.f, 0.f, 0.f};

  for (int k0 = 0; k0 < DM_; k0 += 32) {
    __syncthreads();
#pragma unroll
    for (int i = 0; i < 4; ++i) {
      int c = wave * 4 + i;
      if (c < 8)
        ldg16_lds(A + (size_t)(m0 + c * 16 + srow) * DM_ + k0 + scol, &As[c * 512]);
      else
        ldg16_lds(W + (size_t)(n0 + (c - 8) * 16 + srow) * DM_ + k0 + scol, &Bs[(c - 8) * 512]);
    }
    __syncthreads();
    short8 af[4], bfr[4];
#pragma unroll
    for (int mi = 0; mi < 4; ++mi)
      af[mi] = *(const short8*)&As[(wm * 64 + mi * 16 + l15) * 32 + l4 * 8];
#pragma unroll
    for (int ni = 0; ni < 4; ++ni)
      bfr[ni] = *(const short8*)&Bs[(wn * 64 + ni * 16 + l15) * 32 + l4 * 8];
#pragma unroll
    for (int mi = 0; mi < 4; ++mi)
#pragma unroll
      for (int ni = 0; ni < 4; ++ni)
        acc[mi][ni] = MFMA16(af[mi], bfr[ni], acc[mi][ni]);
  }

#pragma unroll
  for (int mi = 0; mi < 4; ++mi)
#pragma unroll
    for (int ni = 0; ni < 4; ++ni)
#pragma unroll
      for (int r = 0; r < 4; ++r) {
        int m = m0 + wm * 64 + mi * 16 + l4 * 4 + r;
        int n = n0 + wn * 64 + ni * 16 + l15;
        out[(size_t)m * DM_ + n] = acc[mi][ni][r];
      }
}

// ---------------- Flash attention v6 (R9/R12-exact: XCD swizzle, validated ~63us / 12.6MB) ----------------
__global__ __launch_bounds__(256, 2) void attn_k(
    const ushort* __restrict__ Q, const ushort* __restrict__ K, const ushort* __restrict__ Vt,
    const float* __restrict__ biasTab, ushort* __restrict__ Ctx)
{
  __shared__ __align__(16) ushort Ks[2][2][64][32];   // 16 KB [buf][kk][key][dh-half]
  __shared__ __align__(16) ushort Vs[2][2][64][32];   // 16 KB [buf][kk][dh][key-half]
  __shared__ __align__(16) ushort Ps[4][2][16 * 72];  // 18 KB per-wave per-frag P (16q x 64k, stride 72)

  const int tid = threadIdx.x;
  const int wave = tid >> 6, lane = tid & 63;
  const int l15 = lane & 15, l4 = lane >> 4;
  // ---- XCD swizzle: each XCD (lin%8 under round-robin dispatch) owns 4 bh ----
  const int lin = blockIdx.y * 16 + blockIdx.x;
  const int xcd = lin & 7, r8 = lin >> 3;
  const int bh = xcd * 4 + (r8 >> 4);   // b*H + h
  const int qb = (r8 & 15) * 128;
  const int h = bh & (H_ - 1);
  const int b = bh >> 4;
  const int q0 = qb + wave * 32;        // frag A rows [q0,q0+16), frag B rows [q0+16,q0+32)
  const int srow = lane >> 2, scol = (lane & 3) * 8;

  const ushort* Qh = Q  + (size_t)bh * S_ * DH_;
  const ushort* Kh = K  + (size_t)bh * S_ * DH_;
  const ushort* Vh = Vt + (size_t)bh * DH_ * S_;

  // bias idx = h*4095 + 2047 + key - q; key = kt + nt*16 + l15, q = q0 + l4*4 + r
  const float* bpA = biasTab + h * NBIAS_ + 2047 + l15 - (q0 + l4 * 4);

  short8 qfA[2], qfB[2];
#pragma unroll
  for (int kk = 0; kk < 2; ++kk) {
    qfA[kk] = *(const short8*)(Qh + (size_t)(q0 + l15) * DH_ + kk * 32 + l4 * 8);
    qfB[kk] = *(const short8*)(Qh + (size_t)(q0 + 16 + l15) * DH_ + kk * 32 + l4 * 8);
  }

  short8 ones;
#pragma unroll
  for (int i = 0; i < 8; ++i) ones[i] = (short)0x3F80;  // bf16 1.0

  f32x4 ofA[4], ofB[4];
#pragma unroll
  for (int nt = 0; nt < 4; ++nt) { ofA[nt] = (f32x4){0.f,0.f,0.f,0.f}; ofB[nt] = (f32x4){0.f,0.f,0.f,0.f}; }
  f32x4 lsA = (f32x4){0.f,0.f,0.f,0.f}, lsB = (f32x4){0.f,0.f,0.f,0.f};

  ushort* PwA = &Ps[wave][0][0];
  ushort* PwB = &Ps[wave][1][0];

  // ---- prologue: stage tile 0 into buf0, load bias tile 0 ----
#pragma unroll
  for (int i = 0; i < 2; ++i) {
    int c = wave * 2 + i;
    int kk = c >> 2, rg = c & 3;
    ldg16_lds(Kh + (size_t)(rg * 16 + srow) * DH_ + kk * 32 + scol, &Ks[0][0][0][0] + c * 512);
    ldg16_lds(Vh + (size_t)(rg * 16 + srow) * S_ + kk * 32 + scol, &Vs[0][0][0][0] + c * 512);
  }
  float cbX[20], cbY[20];
  {
    const float* pt = bpA;
#pragma unroll
    for (int nt = 0; nt < 4; ++nt)
#pragma unroll
      for (int r = 0; r < 4; ++r) cbX[nt * 4 + r] = pt[nt * 16 - r];
#pragma unroll
    for (int r = 0; r < 4; ++r) cbX[16 + r] = pt[-16 - r];
  }

  int cur = 0;

  auto tile = [&](int kt, float (&cb)[20], float (&nb)[20]) {
    __syncthreads();   // drains vmcnt: buf[cur] staged; prev readers done

    // ---- prefetch next tile: K/V stage into buf^1 + bias into nb (in flight all tile) ----
    if (kt + 64 < S_) {
#pragma unroll
      for (int i = 0; i < 2; ++i) {
        int c = wave * 2 + i;
        int kk = c >> 2, rg = c & 3;
        ldg16_lds(Kh + (size_t)(kt + 64 + rg * 16 + srow) * DH_ + kk * 32 + scol,
                  &Ks[cur ^ 1][0][0][0] + c * 512);
        ldg16_lds(Vh + (size_t)(rg * 16 + srow) * S_ + kt + 64 + kk * 32 + scol,
                  &Vs[cur ^ 1][0][0][0] + c * 512);
      }
      const float* pt = bpA + kt + 64;
#pragma unroll
      for (int nt = 0; nt < 4; ++nt)
#pragma unroll
        for (int r = 0; r < 4; ++r) nb[nt * 4 + r] = pt[nt * 16 - r];
#pragma unroll
      for (int r = 0; r < 4; ++r) nb[16 + r] = pt[-16 - r];
    }

    // ---- QK^T: D[q][key], accumulator initialized with the bias (C-init) ----
    f32x4 scA[4], scB[4];
#pragma unroll
    for (int nt = 0; nt < 4; ++nt) {
      scA[nt] = (f32x4){cb[nt * 4 + 0], cb[nt * 4 + 1], cb[nt * 4 + 2], cb[nt * 4 + 3]};
      if (nt == 0) scB[0] = (f32x4){cb[16], cb[17], cb[18], cb[19]};
      else scB[nt] = (f32x4){cb[(nt - 1) * 4 + 0], cb[(nt - 1) * 4 + 1],
                             cb[(nt - 1) * 4 + 2], cb[(nt - 1) * 4 + 3]};
    }
    __builtin_amdgcn_s_setprio(1);
#pragma unroll
    for (int kk = 0; kk < 2; ++kk)
#pragma unroll
      for (int nt = 0; nt < 4; ++nt) {
        short8 kf = *(const short8*)&Ks[cur][kk][nt * 16 + l15][l4 * 8];
        scA[nt] = MFMA16(qfA[kk], kf, scA[nt]);
        scB[nt] = MFMA16(qfB[kk], kf, scB[nt]);
      }
    __builtin_amdgcn_s_setprio(0);

    // ---- p = exp2(score+bias); scalar bf16 stores ----
#pragma unroll
    for (int nt = 0; nt < 4; ++nt)
#pragma unroll
      for (int r = 0; r < 4; ++r) {
        PwA[(l4 * 4 + r) * 72 + nt * 16 + l15] = f2bf_fast(EXP2(scA[nt][r]));
        PwB[(l4 * 4 + r) * 72 + nt * 16 + l15] = f2bf_fast(EXP2(scB[nt][r]));
      }

    // ---- read P as A-frags (plain b128) ----
    short8 pfA[2], pfB[2];
#pragma unroll
    for (int kk = 0; kk < 2; ++kk) {
      pfA[kk] = *(const short8*)&PwA[l15 * 72 + kk * 32 + l4 * 8];
      pfB[kk] = *(const short8*)&PwB[l15 * 72 + kk * 32 + l4 * 8];
    }

    // ---- PV + row-sums; V single b128 ----
    __builtin_amdgcn_s_setprio(1);
#pragma unroll
    for (int kk = 0; kk < 2; ++kk) {
      lsA = MFMA16(pfA[kk], ones, lsA);
      lsB = MFMA16(pfB[kk], ones, lsB);
#pragma unroll
      for (int nt = 0; nt < 4; ++nt) {
        short8 vf = *(const short8*)&Vs[cur][kk][nt * 16 + l15][l4 * 8];
        ofA[nt] = MFMA16(pfA[kk], vf, ofA[nt]);
        ofB[nt] = MFMA16(pfB[kk], vf, ofB[nt]);
      }
    }
    __builtin_amdgcn_s_setprio(0);
    cur ^= 1;
  };

  for (int kt = 0; kt < S_; kt += 128) {
    tile(kt, cbX, cbY);
    tile(kt + 64, cbY, cbX);
  }

  // ---- finalize: ctx[token][h*64 + dh] ----
  float invA[4], invB[4];
#pragma unroll
  for (int r = 0; r < 4; ++r) { invA[r] = 1.0f / lsA[r]; invB[r] = 1.0f / lsB[r]; }
#pragma unroll
  for (int nt = 0; nt < 4; ++nt)
#pragma unroll
    for (int r = 0; r < 4; ++r) {
      int tA = b * S_ + q0 + l4 * 4 + r;
      Ctx[(size_t)tA * DM_ + h * 64 + nt * 16 + l15] = f2bf(ofA[nt][r] * invA[r]);
      Ctx[(size_t)(tA + 16) * DM_ + h * 64 + nt * 16 + l15] = f2bf(ofB[nt][r] * invB[r]);
    }
}

// ---------------- launch ----------------
extern "C" void kernel_launch(void* const* d_in, const int* in_sizes, int n_in,
                              void* d_out, int out_size, void* d_ws, size_t ws_size,
                              hipStream_t stream) {
  const float* hs  = (const float*)d_in[0];
  const float* Wq  = (const float*)d_in[1];
  const float* Wk  = (const float*)d_in[2];
  const float* Wv  = (const float*)d_in[3];
  const float* Wo  = (const float*)d_in[4];
  const float* rel = (const float*)d_in[5];
  float* out = (float*)d_out;

  ushort* Xb  = (ushort*)d_ws;                         // 4096x1024
  ushort* Wqb = Xb  + (size_t)NTOK_ * DM_;             // 1024x1024 each, contiguous
  ushort* Wkb = Wqb + (size_t)DM_ * DM_;
  ushort* Wvb = Wkb + (size_t)DM_ * DM_;
  ushort* Wob = Wvb + (size_t)DM_ * DM_;
  ushort* Qd  = Wob + (size_t)DM_ * DM_;               // [b][h][s][dh], pre-scaled
  ushort* Kd  = Qd  + (size_t)NTOK_ * DM_;
  ushort* Vtd = Kd  + (size_t)NTOK_ * DM_;             // [b][h][dh][s]
  float* biasTab = (float*)(Vtd + (size_t)NTOK_ * DM_); // [H][4095], pre-scaled by log2(e)
  ushort* Ctx = Xb;                                     // alias: X dead after QKV GEMM

  prep_k<<<CAST_BLKS + 1, 256, 0, stream>>>(hs, Wq, Wk, Wv, Wo, Xb, biasTab, rel);

  gemm_qkv_k<<<dim3(16, 32), 256, 0, stream>>>(Xb, Wqb, Wkb, Wvb, Qd, Kd, Vtd);
  attn_k<<<dim3(S_ / 128, 2 * H_), 256, 0, stream>>>(Qd, Kd, Vtd, biasTab, Ctx);
  gemm_out_k<<<dim3(8, 32), 256, 0, stream>>>(Ctx, Wob, out);
}

// Round 14
// 202.567 us; speedup vs baseline: 1.0177x; 1.0177x over previous
//
#include <hip/hip_runtime.h>
#include <math.h>

// Problem constants (T5 encoder self-attention)
#define H_    16
#define S_    2048
#define DH_   64
#define DM_   1024
#define NTOK_ 4096          // B*S
#define NBIAS_ 4095         // 2*S-1 distinct relative positions

typedef __attribute__((ext_vector_type(8))) short short8;  // 8 bf16 (4 VGPRs)
typedef __attribute__((ext_vector_type(4))) float f32x4;   // MFMA C/D frag

#define MFMA16(a, b, c) __builtin_amdgcn_mfma_f32_16x16x32_bf16((a), (b), (c), 0, 0, 0)

#if __has_builtin(__builtin_amdgcn_exp2f)
#define EXP2(x) __builtin_amdgcn_exp2f(x)
#else
#define EXP2(x) exp2f(x)
#endif

__device__ __forceinline__ ushort f2bf(float f) {
  union { float f; unsigned u; } x; x.f = f;
  unsigned r = (x.u + 0x7FFFu + ((x.u >> 16) & 1u)) >> 16;  // RNE
  return (ushort)r;
}
__device__ __forceinline__ ushort f2bf_fast(float f) {       // round-half-up (2 VALU)
  union { float f; unsigned u; } x; x.f = f;
  return (ushort)((x.u + 0x8000u) >> 16);
}

// global (16B per lane) -> LDS, async. LDS dest = wave-uniform base + lane*16.
__device__ __forceinline__ void ldg16_lds(const ushort* g, ushort* l) {
  __builtin_amdgcn_global_load_lds(
      (const __attribute__((address_space(1))) unsigned int*)g,
      (__attribute__((address_space(3))) unsigned int*)l, 16, 0, 0);
}

// ---------------- fp32 -> bf16 cast, all 5 tensors fused (R12-exact; separate launch
// measured faster than any fusion variant: R11 +3.4us, R13 +3.2us) ----------------
__global__ void cast_all_k(const float* __restrict__ hs,
                           const float* __restrict__ wq, const float* __restrict__ wk,
                           const float* __restrict__ wv, const float* __restrict__ wo,
                           ushort* __restrict__ out) {
  int i = (blockIdx.x * blockDim.x + threadIdx.x) * 4;
  const float* src;
  int off;
  if (i < NTOK_ * DM_) {
    src = hs; off = i;
  } else {
    int j = i - NTOK_ * DM_;
    int w = j >> 20;                           // DM_*DM_ = 2^20
    off = j & ((DM_ * DM_) - 1);
    src = (w == 0) ? wq : (w == 1) ? wk : (w == 2) ? wv : wo;
  }
  const float4 v = *(const float4*)(src + off);
  ushort4 o;
  o.x = f2bf(v.x); o.y = f2bf(v.y); o.z = f2bf(v.z); o.w = f2bf(v.w);
  *(ushort4*)(out + i) = o;
}

// ---------------- T5 relative-position bias table (pre-scaled by log2 e, R12-exact) ----------------
__global__ void build_bias_k(const float* __restrict__ rel_emb, float* __restrict__ biasTab) {
  int d = blockIdx.x * blockDim.x + threadIdx.x;
  if (d >= NBIAS_) return;
  int rp = d - (S_ - 1);
  int ret = (rp > 0) ? 16 : 0;
  int arp = rp < 0 ? -rp : rp;
  int bucket;
  if (arp < 8) {
    bucket = ret + arp;
  } else {
    float t = logf((float)arp * 0.125f);
    t = t / 2.772588722239781f;
    t = t * 8.0f;
    int large = 8 + (int)t;
    if (large > 15) large = 15;
    bucket = ret + large;
  }
  for (int h = 0; h < H_; ++h)
    biasTab[h * NBIAS_ + d] = rel_emb[bucket * H_ + h] * 1.4426950408889634f;
}

// ---------------- QKV projection, z-FUSED (R12-exact, best measured): one X stage, 3 W panels ---------
// Per k-step per wave: 24 MFMA : 10 ds_read : 5 stage chunks. Tile 128(M) x 64(N) x 3 outputs;
// grid (16,32) = 512 = 2/CU; LDS 20KB. Q pre-scaled 0.125*log2e. Removing the 3x-redundant
// X staging of the per-z kernel was worth ~-8us (R12: 209->203 family best).
__global__ __launch_bounds__(256) void gemm_qkv_k(
    const ushort* __restrict__ X,
    const ushort* __restrict__ Wq, const ushort* __restrict__ Wk, const ushort* __restrict__ Wv,
    ushort* __restrict__ Q, ushort* __restrict__ K, ushort* __restrict__ Vt)
{
  __shared__ __align__(16) ushort As[128 * 32];      // 8 KB
  __shared__ __align__(16) ushort Bs[3][64 * 32];    // 12 KB (one 64-row panel per weight)

  const int tid = threadIdx.x;
  const int wave = tid >> 6, lane = tid & 63;
  const int l15 = lane & 15, l4 = lane >> 4;
  const int wm = wave >> 1, wn = wave & 1;
  const int m0 = blockIdx.y * 128;
  const int n0 = blockIdx.x * 64;
  const int srow = lane >> 2, scol = (lane & 3) * 8;

  f32x4 acc[3][4][2];
#pragma unroll
  for (int p = 0; p < 3; ++p)
#pragma unroll
    for (int mi = 0; mi < 4; ++mi)
#pragma unroll
      for (int ni = 0; ni < 2; ++ni) acc[p][mi][ni] = (f32x4){0.f, 0.f, 0.f, 0.f};

  for (int k0 = 0; k0 < DM_; k0 += 32) {
    __syncthreads();   // previous iter's LDS readers done
#pragma unroll
    for (int i = 0; i < 5; ++i) {
      int c = wave * 5 + i;                 // 0..19: 8 A-chunks then 3x4 B-chunks
      if (c < 8) {
        ldg16_lds(X + (size_t)(m0 + c * 16 + srow) * DM_ + k0 + scol, &As[c * 512]);
      } else {
        int j = c - 8;                      // 0..11
        int p = j >> 2, q = j & 3;          // panel, chunk
        const ushort* Wp = (p == 0) ? Wq : (p == 1) ? Wk : Wv;
        ldg16_lds(Wp + (size_t)(n0 + q * 16 + srow) * DM_ + k0 + scol, &Bs[p][q * 512]);
      }
    }
    __syncthreads();   // drains vmcnt (global_load_lds complete)
    short8 af[4], bf[3][2];
#pragma unroll
    for (int mi = 0; mi < 4; ++mi)
      af[mi] = *(const short8*)&As[(wm * 64 + mi * 16 + l15) * 32 + l4 * 8];
#pragma unroll
    for (int p = 0; p < 3; ++p)
#pragma unroll
      for (int ni = 0; ni < 2; ++ni)
        bf[p][ni] = *(const short8*)&Bs[p][(wn * 32 + ni * 16 + l15) * 32 + l4 * 8];
#pragma unroll
    for (int p = 0; p < 3; ++p)
#pragma unroll
      for (int mi = 0; mi < 4; ++mi)
#pragma unroll
        for (int ni = 0; ni < 2; ++ni)
          acc[p][mi][ni] = MFMA16(af[mi], bf[p][ni], acc[p][mi][ni]);
  }

#pragma unroll
  for (int p = 0; p < 3; ++p) {
    const float scl = (p == 0) ? 0.1803368801111137f : 1.0f;  // 0.125 * log2(e) for Q
#pragma unroll
    for (int mi = 0; mi < 4; ++mi)
#pragma unroll
      for (int ni = 0; ni < 2; ++ni)
#pragma unroll
        for (int r = 0; r < 4; ++r) {
          int m = m0 + wm * 64 + mi * 16 + l4 * 4 + r;
          int n = n0 + wn * 32 + ni * 16 + l15;
          int b = m >> 11, s = m & (S_ - 1);
          int h = n >> 6, d = n & 63;
          ushort bv = f2bf(acc[p][mi][ni][r] * scl);
          if (p == 0)      Q [((size_t)(b * H_ + h) * S_ + s) * DH_ + d] = bv;
          else if (p == 1) K [((size_t)(b * H_ + h) * S_ + s) * DH_ + d] = bv;
          else             Vt[((size_t)(b * H_ + h) * DH_ + d) * S_ + s] = bv;
        }
  }
}

// ---------------- Output projection: out = Ctx @ Wo^T (fp32 out, R5/R12-exact) ----------------
__global__ __launch_bounds__(256) void gemm_out_k(
    const ushort* __restrict__ A, const ushort* __restrict__ W, float* __restrict__ out)
{
  __shared__ __align__(16) ushort As[128 * 32];
  __shared__ __align__(16) ushort Bs[128 * 32];
  const int tid = threadIdx.x;
  const int wave = tid >> 6, lane = tid & 63;
  const int l15 = lane & 15, l4 = lane >> 4;
  const int wm = wave >> 1, wn = wave & 1;
  const int m0 = blockIdx.y * 128;
  const int n0 = blockIdx.x * 128;
  const int srow = lane >> 2, scol = (lane & 3) * 8;

  f32x4 acc[4][4];
#pragma unroll
  for (int mi = 0; mi < 4; ++mi)
#pragma unroll
    for (int ni = 0; ni < 4; ++ni) acc[mi][ni] = (f32x4){0.f, 0.f, 0.f, 0.f};

  for (int k0 = 0; k0 < DM_; k0 += 32) {
    __syncthreads();
#pragma unroll
    for (int i = 0; i < 4; ++i) {
      int c = wave * 4 + i;
      if (c < 8)
        ldg16_lds(A + (size_t)(m0 + c * 16 + srow) * DM_ + k0 + scol, &As[c * 512]);
      else
        ldg16_lds(W + (size_t)(n0 + (c - 8) * 16 + srow) * DM_ + k0 + scol, &Bs[(c - 8) * 512]);
    }
    __syncthreads();
    short8 af[4], bfr[4];
#pragma unroll
    for (int mi = 0; mi < 4; ++mi)
      af[mi] = *(const short8*)&As[(wm * 64 + mi * 16 + l15) * 32 + l4 * 8];
#pragma unroll
    for (int ni = 0; ni < 4; ++ni)
      bfr[ni] = *(const short8*)&Bs[(wn * 64 + ni * 16 + l15) * 32 + l4 * 8];
#pragma unroll
    for (int mi = 0; mi < 4; ++mi)
#pragma unroll
      for (int ni = 0; ni < 4; ++ni)
        acc[mi][ni] = MFMA16(af[mi], bfr[ni], acc[mi][ni]);
  }

#pragma unroll
  for (int mi = 0; mi < 4; ++mi)
#pragma unroll
    for (int ni = 0; ni < 4; ++ni)
#pragma unroll
      for (int r = 0; r < 4; ++r) {
        int m = m0 + wm * 64 + mi * 16 + l4 * 4 + r;
        int n = n0 + wn * 64 + ni * 16 + l15;
        out[(size_t)m * DM_ + n] = acc[mi][ni][r];
      }
}

// ---------------- Flash attention v6 (R12-exact: XCD swizzle, validated ~63us / 12.6MB) ----------------
__global__ __launch_bounds__(256, 2) void attn_k(
    const ushort* __restrict__ Q, const ushort* __restrict__ K, const ushort* __restrict__ Vt,
    const float* __restrict__ biasTab, ushort* __restrict__ Ctx)
{
  __shared__ __align__(16) ushort Ks[2][2][64][32];   // 16 KB [buf][kk][key][dh-half]
  __shared__ __align__(16) ushort Vs[2][2][64][32];   // 16 KB [buf][kk][dh][key-half]
  __shared__ __align__(16) ushort Ps[4][2][16 * 72];  // 18 KB per-wave per-frag P (16q x 64k, stride 72)

  const int tid = threadIdx.x;
  const int wave = tid >> 6, lane = tid & 63;
  const int l15 = lane & 15, l4 = lane >> 4;
  // ---- XCD swizzle: each XCD (lin%8 under round-robin dispatch) owns 4 bh ----
  const int lin = blockIdx.y * 16 + blockIdx.x;
  const int xcd = lin & 7, r8 = lin >> 3;
  const int bh = xcd * 4 + (r8 >> 4);   // b*H + h
  const int qb = (r8 & 15) * 128;
  const int h = bh & (H_ - 1);
  const int b = bh >> 4;
  const int q0 = qb + wave * 32;        // frag A rows [q0,q0+16), frag B rows [q0+16,q0+32)
  const int srow = lane >> 2, scol = (lane & 3) * 8;

  const ushort* Qh = Q  + (size_t)bh * S_ * DH_;
  const ushort* Kh = K  + (size_t)bh * S_ * DH_;
  const ushort* Vh = Vt + (size_t)bh * DH_ * S_;

  // bias idx = h*4095 + 2047 + key - q; key = kt + nt*16 + l15, q = q0 + l4*4 + r
  const float* bpA = biasTab + h * NBIAS_ + 2047 + l15 - (q0 + l4 * 4);

  short8 qfA[2], qfB[2];
#pragma unroll
  for (int kk = 0; kk < 2; ++kk) {
    qfA[kk] = *(const short8*)(Qh + (size_t)(q0 + l15) * DH_ + kk * 32 + l4 * 8);
    qfB[kk] = *(const short8*)(Qh + (size_t)(q0 + 16 + l15) * DH_ + kk * 32 + l4 * 8);
  }

  short8 ones;
#pragma unroll
  for (int i = 0; i < 8; ++i) ones[i] = (short)0x3F80;  // bf16 1.0

  f32x4 ofA[4], ofB[4];
#pragma unroll
  for (int nt = 0; nt < 4; ++nt) { ofA[nt] = (f32x4){0.f,0.f,0.f,0.f}; ofB[nt] = (f32x4){0.f,0.f,0.f,0.f}; }
  f32x4 lsA = (f32x4){0.f,0.f,0.f,0.f}, lsB = (f32x4){0.f,0.f,0.f,0.f};

  ushort* PwA = &Ps[wave][0][0];
  ushort* PwB = &Ps[wave][1][0];

  // ---- prologue: stage tile 0 into buf0, load bias tile 0 ----
#pragma unroll
  for (int i = 0; i < 2; ++i) {
    int c = wave * 2 + i;
    int kk = c >> 2, rg = c & 3;
    ldg16_lds(Kh + (size_t)(rg * 16 + srow) * DH_ + kk * 32 + scol, &Ks[0][0][0][0] + c * 512);
    ldg16_lds(Vh + (size_t)(rg * 16 + srow) * S_ + kk * 32 + scol, &Vs[0][0][0][0] + c * 512);
  }
  float cbX[20], cbY[20];
  {
    const float* pt = bpA;
#pragma unroll
    for (int nt = 0; nt < 4; ++nt)
#pragma unroll
      for (int r = 0; r < 4; ++r) cbX[nt * 4 + r] = pt[nt * 16 - r];
#pragma unroll
    for (int r = 0; r < 4; ++r) cbX[16 + r] = pt[-16 - r];
  }

  int cur = 0;

  auto tile = [&](int kt, float (&cb)[20], float (&nb)[20]) {
    __syncthreads();   // drains vmcnt: buf[cur] staged; prev readers done

    // ---- prefetch next tile: K/V stage into buf^1 + bias into nb (in flight all tile) ----
    if (kt + 64 < S_) {
#pragma unroll
      for (int i = 0; i < 2; ++i) {
        int c = wave * 2 + i;
        int kk = c >> 2, rg = c & 3;
        ldg16_lds(Kh + (size_t)(kt + 64 + rg * 16 + srow) * DH_ + kk * 32 + scol,
                  &Ks[cur ^ 1][0][0][0] + c * 512);
        ldg16_lds(Vh + (size_t)(rg * 16 + srow) * S_ + kt + 64 + kk * 32 + scol,
                  &Vs[cur ^ 1][0][0][0] + c * 512);
      }
      const float* pt = bpA + kt + 64;
#pragma unroll
      for (int nt = 0; nt < 4; ++nt)
#pragma unroll
        for (int r = 0; r < 4; ++r) nb[nt * 4 + r] = pt[nt * 16 - r];
#pragma unroll
      for (int r = 0; r < 4; ++r) nb[16 + r] = pt[-16 - r];
    }

    // ---- QK^T: D[q][key], accumulator initialized with the bias (C-init) ----
    f32x4 scA[4], scB[4];
#pragma unroll
    for (int nt = 0; nt < 4; ++nt) {
      scA[nt] = (f32x4){cb[nt * 4 + 0], cb[nt * 4 + 1], cb[nt * 4 + 2], cb[nt * 4 + 3]};
      if (nt == 0) scB[0] = (f32x4){cb[16], cb[17], cb[18], cb[19]};
      else scB[nt] = (f32x4){cb[(nt - 1) * 4 + 0], cb[(nt - 1) * 4 + 1],
                             cb[(nt - 1) * 4 + 2], cb[(nt - 1) * 4 + 3]};
    }
    __builtin_amdgcn_s_setprio(1);
#pragma unroll
    for (int kk = 0; kk < 2; ++kk)
#pragma unroll
      for (int nt = 0; nt < 4; ++nt) {
        short8 kf = *(const short8*)&Ks[cur][kk][nt * 16 + l15][l4 * 8];
        scA[nt] = MFMA16(qfA[kk], kf, scA[nt]);
        scB[nt] = MFMA16(qfB[kk], kf, scB[nt]);
      }
    __builtin_amdgcn_s_setprio(0);

    // ---- p = exp2(score+bias); scalar bf16 stores ----
#pragma unroll
    for (int nt = 0; nt < 4; ++nt)
#pragma unroll
      for (int r = 0; r < 4; ++r) {
        PwA[(l4 * 4 + r) * 72 + nt * 16 + l15] = f2bf_fast(EXP2(scA[nt][r]));
        PwB[(l4 * 4 + r) * 72 + nt * 16 + l15] = f2bf_fast(EXP2(scB[nt][r]));
      }

    // ---- read P as A-frags (plain b128) ----
    short8 pfA[2], pfB[2];
#pragma unroll
    for (int kk = 0; kk < 2; ++kk) {
      pfA[kk] = *(const short8*)&PwA[l15 * 72 + kk * 32 + l4 * 8];
      pfB[kk] = *(const short8*)&PwB[l15 * 72 + kk * 32 + l4 * 8];
    }

    // ---- PV + row-sums; V single b128 ----
    __builtin_amdgcn_s_setprio(1);
#pragma unroll
    for (int kk = 0; kk < 2; ++kk) {
      lsA = MFMA16(pfA[kk], ones, lsA);
      lsB = MFMA16(pfB[kk], ones, lsB);
#pragma unroll
      for (int nt = 0; nt < 4; ++nt) {
        short8 vf = *(const short8*)&Vs[cur][kk][nt * 16 + l15][l4 * 8];
        ofA[nt] = MFMA16(pfA[kk], vf, ofA[nt]);
        ofB[nt] = MFMA16(pfB[kk], vf, ofB[nt]);
      }
    }
    __builtin_amdgcn_s_setprio(0);
    cur ^= 1;
  };

  for (int kt = 0; kt < S_; kt += 128) {
    tile(kt, cbX, cbY);
    tile(kt + 64, cbY, cbX);
  }

  // ---- finalize: ctx[token][h*64 + dh] ----
  float invA[4], invB[4];
#pragma unroll
  for (int r = 0; r < 4; ++r) { invA[r] = 1.0f / lsA[r]; invB[r] = 1.0f / lsB[r]; }
#pragma unroll
  for (int nt = 0; nt < 4; ++nt)
#pragma unroll
    for (int r = 0; r < 4; ++r) {
      int tA = b * S_ + q0 + l4 * 4 + r;
      Ctx[(size_t)tA * DM_ + h * 64 + nt * 16 + l15] = f2bf(ofA[nt][r] * invA[r]);
      Ctx[(size_t)(tA + 16) * DM_ + h * 64 + nt * 16 + l15] = f2bf(ofB[nt][r] * invB[r]);
    }
}

// ---------------- launch ----------------
extern "C" void kernel_launch(void* const* d_in, const int* in_sizes, int n_in,
                              void* d_out, int out_size, void* d_ws, size_t ws_size,
                              hipStream_t stream) {
  const float* hs  = (const float*)d_in[0];
  const float* Wq  = (const float*)d_in[1];
  const float* Wk  = (const float*)d_in[2];
  const float* Wv  = (const float*)d_in[3];
  const float* Wo  = (const float*)d_in[4];
  const float* rel = (const float*)d_in[5];
  float* out = (float*)d_out;

  ushort* Xb  = (ushort*)d_ws;                         // 4096x1024
  ushort* Wqb = Xb  + (size_t)NTOK_ * DM_;             // 1024x1024 each, contiguous
  ushort* Wkb = Wqb + (size_t)DM_ * DM_;
  ushort* Wvb = Wkb + (size_t)DM_ * DM_;
  ushort* Wob = Wvb + (size_t)DM_ * DM_;
  ushort* Qd  = Wob + (size_t)DM_ * DM_;               // [b][h][s][dh], pre-scaled
  ushort* Kd  = Qd  + (size_t)NTOK_ * DM_;
  ushort* Vtd = Kd  + (size_t)NTOK_ * DM_;             // [b][h][dh][s]
  float* biasTab = (float*)(Vtd + (size_t)NTOK_ * DM_); // [H][4095], pre-scaled by log2(e)
  ushort* Ctx = Xb;                                     // alias: X dead after QKV GEMM

  cast_all_k<<<(NTOK_ * DM_ + 4 * DM_ * DM_) / (4 * 256), 256, 0, stream>>>(hs, Wq, Wk, Wv, Wo, Xb);
  build_bias_k<<<16, 256, 0, stream>>>(rel, biasTab);

  gemm_qkv_k<<<dim3(16, 32), 256, 0, stream>>>(Xb, Wqb, Wkb, Wvb, Qd, Kd, Vtd);
  attn_k<<<dim3(S_ / 128, 2 * H_), 256, 0, stream>>>(Qd, Kd, Vtd, biasTab, Ctx);
  gemm_out_k<<<dim3(8, 32), 256, 0, stream>>>(Ctx, Wob, out);
}